// Round 7
// baseline (28.744 us; speedup 1.0000x reference)
//
#include <hip/hip_runtime.h>
#include <hip/hip_bf16.h>
#include <math.h>

#define N_SYS   64
#define N_ELEC  64
#define NTOT    (N_SYS * N_ELEC)   // 4096
#define DIM     256
#define HEADS   8
#define LN_EPS  1e-6f

typedef __attribute__((ext_vector_type(8))) short bf16x8;
typedef __attribute__((ext_vector_type(4))) short short4v;
typedef __attribute__((ext_vector_type(4))) float f32x4;

static __device__ __forceinline__ short f2bf(float f) {
    __hip_bfloat16 h = __float2bfloat16(f);
    return *reinterpret_cast<short*>(&h);
}

// ---------------------------------------------------------------------------
// K1: blocks 0..255 : fused qkv GEMM + attention for (head h, system pair p).
//       bid = h*32 + p  ->  bid%8 == p%8: a pair's 8 head-blocks share an XCD
//       so the pair's h_one slice (128 KB) is fetched into one L2 once.
//       512 threads = 8 waves; waves 0-3 -> system 2p, waves 4-7 -> 2p+1.
//       A fragments are read direct global->reg (wave-exclusive rows);
//       B (W_qkv head slice) is staged once per block, shared by both systems.
//     blocks 256..271: transpose-cast Wout/Wmlp f32 [K][N] -> bf16 [N][K],
//       2 tiles per block (512 thr).
// ---------------------------------------------------------------------------
__global__ __launch_bounds__(512, 4) void k1_qkv_attn(
    const float* __restrict__ h_one, const float* __restrict__ W_qkv,
    const float* __restrict__ Wout, const float* __restrict__ Wmlp,
    short* __restrict__ attn, short* __restrict__ WoutT,
    short* __restrict__ WmlpT)
{
    const int tid = threadIdx.x;

    if (blockIdx.x >= 256) {
        // ---- weight transpose tiles (64x64), 2 per block
        const int t2 = (blockIdx.x - 256) * 2 + (tid >> 8);   // 0..31
        const int ltid = tid & 255;
        const float* src = (t2 < 16) ? Wout : Wmlp;
        short* dst = (t2 < 16) ? WoutT : WmlpT;
        const int tile = t2 & 15;
        const int tk = (tile >> 2) * 64, tn = (tile & 3) * 64;
#pragma unroll
        for (int p = 0; p < 4; ++p) {
            int idx = p * 256 + ltid;
            int kk = idx >> 4, n4 = (idx & 15) * 4;
            float4 v = *(const float4*)&src[(size_t)(tk + kk) * 256 + tn + n4];
            dst[(size_t)(tn + n4 + 0) * 256 + tk + kk] = f2bf(v.x);
            dst[(size_t)(tn + n4 + 1) * 256 + tk + kk] = f2bf(v.y);
            dst[(size_t)(tn + n4 + 2) * 256 + tk + kk] = f2bf(v.z);
            dst[(size_t)(tn + n4 + 3) * 256 + tk + kk] = f2bf(v.w);
        }
        return;
    }

    const int h = blockIdx.x >> 5;      // head 0..7
    const int p = blockIdx.x & 31;      // system pair 0..31

    __shared__ short Bs[96][72];        // W_qkv^T head slice k-step [n][k]
    __shared__ short Qs[2][64][40];     // per-system Q [i][d]
    __shared__ short Ks[2][64][40];     // per-system K [j][d]
    __shared__ short Vt[2][32][72];     // per-system V^T [d][j]
    __shared__ short Pm[2][64][72];     // per-system P [i][j]

    const int lane = tid & 63;
    const int w = tid >> 6;             // 0..7
    const int sysw = w >> 2;            // 0/1 within pair
    const int wl = w & 3;               // wave within system
    const int l15 = lane & 15;
    const int l4 = lane >> 4;

    const int s = p * 2 + sysw;         // system

    // per-lane A row pointer (wave-exclusive rows)
    const float* Arow = h_one + ((size_t)s * 64 + wl * 16 + l15) * 256;

    const int bkk = tid >> 3;           // 0..63: k row within step
    const int btt = tid & 7;            // float4 chunk phase

    f32x4 acc[6] = {};

    for (int k0 = 0; k0 < 256; k0 += 64) {
        if (k0) __syncthreads();        // protect prior-iteration Bs reads
        // B staging: 96 n-rows x 64 k, 12 f32/thread
#pragma unroll
        for (int q = 0; q < 3; ++q) {
            int c = btt + q * 8;        // float4 chunk 0..23
            int g = c >> 3;             // 0=Q, 1=K, 2=V
            int c4 = (c & 7) * 4;       // col offset within 32
            float4 v = *(const float4*)&W_qkv[(size_t)(k0 + bkk) * 768 + g * 256 + h * 32 + c4];
            Bs[g * 32 + c4 + 0][bkk] = f2bf(v.x);
            Bs[g * 32 + c4 + 1][bkk] = f2bf(v.y);
            Bs[g * 32 + c4 + 2][bkk] = f2bf(v.z);
            Bs[g * 32 + c4 + 3][bkk] = f2bf(v.w);
        }
        __syncthreads();
#pragma unroll
        for (int ki = 0; ki < 2; ++ki) {
            // A fragment direct from global (row l15-owned, 8 consecutive k)
            const float* ap = Arow + k0 + ki * 32 + l4 * 8;
            float4 a0 = *(const float4*)ap;
            float4 a1 = *(const float4*)(ap + 4);
            bf16x8 af;
            af[0] = f2bf(a0.x); af[1] = f2bf(a0.y); af[2] = f2bf(a0.z); af[3] = f2bf(a0.w);
            af[4] = f2bf(a1.x); af[5] = f2bf(a1.y); af[6] = f2bf(a1.z); af[7] = f2bf(a1.w);
#pragma unroll
            for (int nf = 0; nf < 6; ++nf) {
                bf16x8 bfv = *(const bf16x8*)&Bs[nf * 16 + l15][ki * 32 + l4 * 8];
                acc[nf] = __builtin_amdgcn_mfma_f32_16x16x32_bf16(af, bfv, acc[nf], 0, 0, 0);
            }
        }
    }

    // scatter Q, K, V^T (C-layout: row = wl*16 + l4*4 + j, col = nf*16 + l15)
#pragma unroll
    for (int nf = 0; nf < 6; ++nf) {
        int c = nf * 16 + l15;
#pragma unroll
        for (int j = 0; j < 4; ++j) {
            int row = wl * 16 + l4 * 4 + j;
            short v = f2bf(acc[nf][j]);
            if (c < 32)       Qs[sysw][row][c] = v;
            else if (c < 64)  Ks[sysw][row][c - 32] = v;
            else              Vt[sysw][c - 64][row] = v;
        }
    }
    __syncthreads();

    // S^T = K @ Q^T : wave holds j-rows [wl*16,+16), i-cols 0..63 of its system.
    // Column softmax (over i) fully in-wave: i spans {nf, l15}.
    const float scale = 0.17677669529663687f;  // 1/sqrt(32)
    f32x4 sacc[4] = {};
    {
        bf16x8 ak = *(const bf16x8*)&Ks[sysw][wl * 16 + l15][l4 * 8];
#pragma unroll
        for (int nf = 0; nf < 4; ++nf) {
            bf16x8 bq = *(const bf16x8*)&Qs[sysw][nf * 16 + l15][l4 * 8];
            sacc[nf] = __builtin_amdgcn_mfma_f32_16x16x32_bf16(ak, bq, sacc[nf], 0, 0, 0);
        }
    }
#pragma unroll
    for (int nf = 0; nf < 4; ++nf) sacc[nf] *= scale;
#pragma unroll
    for (int jj = 0; jj < 4; ++jj) {
        float mx = fmaxf(fmaxf(sacc[0][jj], sacc[1][jj]),
                         fmaxf(sacc[2][jj], sacc[3][jj]));
        mx = fmaxf(mx, __shfl_xor(mx, 1, 64));
        mx = fmaxf(mx, __shfl_xor(mx, 2, 64));
        mx = fmaxf(mx, __shfl_xor(mx, 4, 64));
        mx = fmaxf(mx, __shfl_xor(mx, 8, 64));
        float e0 = __expf(sacc[0][jj] - mx);
        float e1 = __expf(sacc[1][jj] - mx);
        float e2 = __expf(sacc[2][jj] - mx);
        float e3 = __expf(sacc[3][jj] - mx);
        float ss = e0 + e1 + e2 + e3;
        ss += __shfl_xor(ss, 1, 64);
        ss += __shfl_xor(ss, 2, 64);
        ss += __shfl_xor(ss, 4, 64);
        ss += __shfl_xor(ss, 8, 64);
        float inv = 1.0f / ss;
        sacc[0][jj] = e0 * inv; sacc[1][jj] = e1 * inv;
        sacc[2][jj] = e2 * inv; sacc[3][jj] = e3 * inv;
    }
    // write P[i][j]: i = nf*16+l15, j-quad = wl*16 + l4*4 (b64 stores)
#pragma unroll
    for (int nf = 0; nf < 4; ++nf) {
        short4v pq;
        pq[0] = f2bf(sacc[nf][0]); pq[1] = f2bf(sacc[nf][1]);
        pq[2] = f2bf(sacc[nf][2]); pq[3] = f2bf(sacc[nf][3]);
        *(short4v*)&Pm[sysw][nf * 16 + l15][wl * 16 + l4 * 4] = pq;
    }
    __syncthreads();

    // attn = P @ V : wave rows [wl*16,+16), cols d 0..31
    f32x4 pv[2] = {};
#pragma unroll
    for (int ki = 0; ki < 2; ++ki) {
        bf16x8 ap = *(const bf16x8*)&Pm[sysw][wl * 16 + l15][ki * 32 + l4 * 8];
#pragma unroll
        for (int nf = 0; nf < 2; ++nf) {
            bf16x8 bv = *(const bf16x8*)&Vt[sysw][nf * 16 + l15][ki * 32 + l4 * 8];
            pv[nf] = __builtin_amdgcn_mfma_f32_16x16x32_bf16(ap, bv, pv[nf], 0, 0, 0);
        }
    }
#pragma unroll
    for (int nf = 0; nf < 2; ++nf)
#pragma unroll
        for (int j = 0; j < 4; ++j)
            attn[(size_t)(s * 64 + wl * 16 + l4 * 4 + j) * 256 + h * 32 + nf * 16 + l15]
                = f2bf(pv[nf][j]);
}

// ---------------------------------------------------------------------------
// K2: fused tail for 16 rows: out-proj+residual, LN1, MLP(silu)+residual, LN2.
// Grid 256 blocks x 512 threads (8 waves). Weight fragments read from global.
// ---------------------------------------------------------------------------
__global__ __launch_bounds__(512) void k2_tail(
    const short* __restrict__ attnbf, const short* __restrict__ WoutT,
    const short* __restrict__ WmlpT, const float* __restrict__ h_one,
    const float* __restrict__ b_mlp,
    const float* __restrict__ ln1_s, const float* __restrict__ ln1_b,
    const float* __restrict__ ln2_s, const float* __restrict__ ln2_b,
    float* __restrict__ out)
{
    const int r0 = blockIdx.x * 16;

    __shared__ short Abf[16][264];
    __shared__ float H1[16][260];
    __shared__ short L1[16][264];

    const int tid = threadIdx.x;
    const int lane = tid & 63;
    const int w = tid >> 6;           // 0..7
    const int l15 = lane & 15;
    const int l4 = lane >> 4;

    {
        int r = tid >> 5, c8 = (tid & 31) * 8;
        *(bf16x8*)&Abf[r][c8] = *(const bf16x8*)&attnbf[(size_t)(r0 + r) * 256 + c8];
    }
    __syncthreads();

    // GEMM1: wave w covers cols [w*32, +32), M=16, K=256
    f32x4 acc[2] = {};
    for (int k0 = 0; k0 < 256; k0 += 32) {
        bf16x8 af = *(const bf16x8*)&Abf[l15][k0 + l4 * 8];
#pragma unroll
        for (int nf = 0; nf < 2; ++nf) {
            int n = w * 32 + nf * 16 + l15;
            bf16x8 bf = *(const bf16x8*)&WoutT[(size_t)n * 256 + k0 + l4 * 8];
            acc[nf] = __builtin_amdgcn_mfma_f32_16x16x32_bf16(af, bf, acc[nf], 0, 0, 0);
        }
    }
#pragma unroll
    for (int nf = 0; nf < 2; ++nf) {
        int col = w * 32 + nf * 16 + l15;
#pragma unroll
        for (int j = 0; j < 4; ++j) {
            int row = l4 * 4 + j;
            H1[row][col] = acc[nf][j] + h_one[(size_t)(r0 + row) * 256 + col];
        }
    }
    __syncthreads();

    // LN1
    {
        float4 sc = *(const float4*)&ln1_s[lane * 4];
        float4 bi = *(const float4*)&ln1_b[lane * 4];
#pragma unroll
        for (int rr = 0; rr < 2; ++rr) {
            int row = w * 2 + rr;
            float4 v = *(const float4*)&H1[row][lane * 4];
            float su = v.x + v.y + v.z + v.w;
#pragma unroll
            for (int off = 32; off > 0; off >>= 1) su += __shfl_xor(su, off, 64);
            float mu = su * (1.0f / 256.0f);
            float dx = v.x - mu, dy = v.y - mu, dz = v.z - mu, dw = v.w - mu;
            float s2 = dx * dx + dy * dy + dz * dz + dw * dw;
#pragma unroll
            for (int off = 32; off > 0; off >>= 1) s2 += __shfl_xor(s2, off, 64);
            float inv = rsqrtf(s2 * (1.0f / 256.0f) + LN_EPS);
            float4 o;
            o.x = dx * inv * sc.x + bi.x;
            o.y = dy * inv * sc.y + bi.y;
            o.z = dz * inv * sc.z + bi.z;
            o.w = dw * inv * sc.w + bi.w;
            *(float4*)&H1[row][lane * 4] = o;
            short4v ob;
            ob[0] = f2bf(o.x); ob[1] = f2bf(o.y); ob[2] = f2bf(o.z); ob[3] = f2bf(o.w);
            *(short4v*)&L1[row][lane * 4] = ob;
        }
    }
    __syncthreads();

    // GEMM2: h2 = H1 + silu(L1 @ WmlpT + b_mlp)
    f32x4 acc2[2] = {};
    for (int k0 = 0; k0 < 256; k0 += 32) {
        bf16x8 af = *(const bf16x8*)&L1[l15][k0 + l4 * 8];
#pragma unroll
        for (int nf = 0; nf < 2; ++nf) {
            int n = w * 32 + nf * 16 + l15;
            bf16x8 bf = *(const bf16x8*)&WmlpT[(size_t)n * 256 + k0 + l4 * 8];
            acc2[nf] = __builtin_amdgcn_mfma_f32_16x16x32_bf16(af, bf, acc2[nf], 0, 0, 0);
        }
    }
#pragma unroll
    for (int nf = 0; nf < 2; ++nf) {
        int col = w * 32 + nf * 16 + l15;
        float bm = b_mlp[col];
#pragma unroll
        for (int j = 0; j < 4; ++j) {
            int row = l4 * 4 + j;
            float v = acc2[nf][j] + bm;
            float sg = 1.0f / (1.0f + __expf(-v));
            H1[row][col] = H1[row][col] + v * sg;   // same-lane RMW
        }
    }
    __syncthreads();

    // LN2 -> out
    {
        float4 sc = *(const float4*)&ln2_s[lane * 4];
        float4 bi = *(const float4*)&ln2_b[lane * 4];
#pragma unroll
        for (int rr = 0; rr < 2; ++rr) {
            int row = w * 2 + rr;
            float4 v = *(const float4*)&H1[row][lane * 4];
            float su = v.x + v.y + v.z + v.w;
#pragma unroll
            for (int off = 32; off > 0; off >>= 1) su += __shfl_xor(su, off, 64);
            float mu = su * (1.0f / 256.0f);
            float dx = v.x - mu, dy = v.y - mu, dz = v.z - mu, dw = v.w - mu;
            float s2 = dx * dx + dy * dy + dz * dz + dw * dw;
#pragma unroll
            for (int off = 32; off > 0; off >>= 1) s2 += __shfl_xor(s2, off, 64);
            float inv = rsqrtf(s2 * (1.0f / 256.0f) + LN_EPS);
            float4 o;
            o.x = dx * inv * sc.x + bi.x;
            o.y = dy * inv * sc.y + bi.y;
            o.z = dz * inv * sc.z + bi.z;
            o.w = dw * inv * sc.w + bi.w;
            *(float4*)&out[(size_t)(r0 + row) * 256 + lane * 4] = o;
        }
    }
}

// ---------------------------------------------------------------------------
extern "C" void kernel_launch(void* const* d_in, const int* in_sizes, int n_in,
                              void* d_out, int out_size, void* d_ws, size_t ws_size,
                              hipStream_t stream)
{
    const float* h_one = (const float*)d_in[0];
    const float* W_qkv = (const float*)d_in[1];
    const float* W_out = (const float*)d_in[2];
    const float* ln1_s = (const float*)d_in[3];
    const float* ln1_b = (const float*)d_in[4];
    const float* W_mlp = (const float*)d_in[5];
    const float* b_mlp = (const float*)d_in[6];
    const float* ln2_s = (const float*)d_in[7];
    const float* ln2_b = (const float*)d_in[8];
    float* out = (float*)d_out;

    char* ws = (char*)d_ws;
    short* attn_bf = (short*)ws;                 // 4096*256 bf16 = 2MB
    short* WoutT   = (short*)(ws + 2097152);     // 256*256 bf16 = 128KB
    short* WmlpT   = WoutT + 256 * 256;

    k1_qkv_attn<<<272, 512, 0, stream>>>(h_one, W_qkv, W_out, W_mlp,
                                         attn_bf, WoutT, WmlpT);
    k2_tail<<<256, 512, 0, stream>>>(attn_bf, WoutT, WmlpT, h_one, b_mlp,
                                     ln1_s, ln1_b, ln2_s, ln2_b, out);
}

// Round 8
// 25.882 us; speedup vs baseline: 1.1106x; 1.1106x over previous
//
#include <hip/hip_runtime.h>
#include <hip/hip_bf16.h>
#include <math.h>

#define N_SYS   64
#define N_ELEC  64
#define NTOT    (N_SYS * N_ELEC)   // 4096
#define DIM     256
#define HEADS   8
#define LN_EPS  1e-6f

typedef __attribute__((ext_vector_type(8))) short bf16x8;
typedef __attribute__((ext_vector_type(4))) short short4v;
typedef __attribute__((ext_vector_type(4))) float f32x4;

static __device__ __forceinline__ short f2bf(float f) {
    __hip_bfloat16 h = __float2bfloat16(f);
    return *reinterpret_cast<short*>(&h);
}

// ---------------------------------------------------------------------------
// K1: blocks 0..511 : fused qkv-slice GEMM + attention for one (system, head).
//     s = b & 63, h = b >> 6 -> a system's 8 head-blocks share an XCD.
//     K-loop staging is register double-buffered (T14): next K-step's global
//     loads are issued before the current step's MFMAs, hiding load latency.
//     blocks 512..543: transpose-cast Wout/Wmlp f32 [K][N] -> bf16 [N][K].
// 256 threads = 4 waves.
// ---------------------------------------------------------------------------
__global__ __launch_bounds__(256) void k1_qkv_attn(
    const float* __restrict__ h_one, const float* __restrict__ W_qkv,
    const float* __restrict__ Wout, const float* __restrict__ Wmlp,
    short* __restrict__ attn, short* __restrict__ WoutT,
    short* __restrict__ WmlpT)
{
    const int tid = threadIdx.x;

    if (blockIdx.x >= 512) {
        // ---- weight transpose tiles (64x64)
        const int b2 = blockIdx.x - 512;
        const float* src = (b2 < 16) ? Wout : Wmlp;
        short* dst = (b2 < 16) ? WoutT : WmlpT;
        const int tile = b2 & 15;
        const int tk = (tile >> 2) * 64, tn = (tile & 3) * 64;
#pragma unroll
        for (int p = 0; p < 4; ++p) {
            int idx = p * 256 + tid;
            int kk = idx >> 4, n4 = (idx & 15) * 4;
            float4 v = *(const float4*)&src[(size_t)(tk + kk) * 256 + tn + n4];
            dst[(size_t)(tn + n4 + 0) * 256 + tk + kk] = f2bf(v.x);
            dst[(size_t)(tn + n4 + 1) * 256 + tk + kk] = f2bf(v.y);
            dst[(size_t)(tn + n4 + 2) * 256 + tk + kk] = f2bf(v.z);
            dst[(size_t)(tn + n4 + 3) * 256 + tk + kk] = f2bf(v.w);
        }
        return;
    }

    const int s = blockIdx.x & 63;     // XCD-colocating map
    const int h = blockIdx.x >> 6;

    __shared__ short Ha[64][72];    // A k-slice (bf16 of h_one rows)
    __shared__ short Bs[96][72];    // B^T k-slice: Bs[n][k] = W_qkv[k][col(n)]
    __shared__ short Qs[64][40];    // Q [i][d]
    __shared__ short Ks[64][40];    // K [j][d]
    __shared__ short Vt[32][72];    // V^T [d][j]
    __shared__ short Pm[64][72];    // P bf16 [i][j]

    const int lane = tid & 63;
    const int w = tid >> 6;
    const int l15 = lane & 15;
    const int l4 = lane >> 4;

    const float* Abase = h_one + (size_t)s * 64 * 256;
    const int rA = tid >> 3;          // A row (and row+32)
    const int cA8 = (tid & 7) * 8;    // A k-chunk
    const int bkk = tid >> 2;         // B: k row within step
    const int btt = tid & 3;          // B: float4 chunk phase

    // register staging buffers (double-buffered)
    float4 ra[2][4];
    float4 rb[2][6];

#define K1_LOAD(buf, kbase)                                                        \
    do {                                                                           \
        const float* ap0 = &Abase[(size_t)rA * 256 + (kbase) + cA8];               \
        const float* ap1 = &Abase[(size_t)(rA + 32) * 256 + (kbase) + cA8];        \
        ra[buf][0] = *(const float4*)ap0;                                          \
        ra[buf][1] = *(const float4*)(ap0 + 4);                                    \
        ra[buf][2] = *(const float4*)ap1;                                          \
        ra[buf][3] = *(const float4*)(ap1 + 4);                                    \
        _Pragma("unroll")                                                          \
        for (int q = 0; q < 6; ++q) {                                              \
            int c = btt + q * 4;                                                   \
            int g = c >> 3;                                                        \
            int c4 = (c & 7) * 4;                                                  \
            rb[buf][q] = *(const float4*)&W_qkv[(size_t)((kbase) + bkk) * 768      \
                                                + g * 256 + h * 32 + c4];          \
        }                                                                          \
    } while (0)

    f32x4 acc[6] = {};

    K1_LOAD(0, 0);

#pragma unroll
    for (int kk = 0; kk < 4; ++kk) {
        const int k0 = kk * 64;
        const int cur = kk & 1;
        const int nxt = cur ^ 1;

        if (kk) __syncthreads();      // prior-iteration LDS reads done
        // LDS writes from current register buffer
        {
            bf16x8 o;
            o[0] = f2bf(ra[cur][0].x); o[1] = f2bf(ra[cur][0].y);
            o[2] = f2bf(ra[cur][0].z); o[3] = f2bf(ra[cur][0].w);
            o[4] = f2bf(ra[cur][1].x); o[5] = f2bf(ra[cur][1].y);
            o[6] = f2bf(ra[cur][1].z); o[7] = f2bf(ra[cur][1].w);
            *(bf16x8*)&Ha[rA][cA8] = o;
            o[0] = f2bf(ra[cur][2].x); o[1] = f2bf(ra[cur][2].y);
            o[2] = f2bf(ra[cur][2].z); o[3] = f2bf(ra[cur][2].w);
            o[4] = f2bf(ra[cur][3].x); o[5] = f2bf(ra[cur][3].y);
            o[6] = f2bf(ra[cur][3].z); o[7] = f2bf(ra[cur][3].w);
            *(bf16x8*)&Ha[rA + 32][cA8] = o;
        }
#pragma unroll
        for (int q = 0; q < 6; ++q) {
            int c = btt + q * 4;
            int g = c >> 3;
            int c4 = (c & 7) * 4;
            Bs[g * 32 + c4 + 0][bkk] = f2bf(rb[cur][q].x);
            Bs[g * 32 + c4 + 1][bkk] = f2bf(rb[cur][q].y);
            Bs[g * 32 + c4 + 2][bkk] = f2bf(rb[cur][q].z);
            Bs[g * 32 + c4 + 3][bkk] = f2bf(rb[cur][q].w);
        }
        // issue next K-step's loads (latency hides under MFMA below)
        if (kk < 3) K1_LOAD(nxt, k0 + 64);
        __syncthreads();

#pragma unroll
        for (int ki = 0; ki < 2; ++ki) {
            bf16x8 af = *(const bf16x8*)&Ha[w * 16 + l15][ki * 32 + l4 * 8];
#pragma unroll
            for (int nf = 0; nf < 6; ++nf) {
                bf16x8 bfv = *(const bf16x8*)&Bs[nf * 16 + l15][ki * 32 + l4 * 8];
                acc[nf] = __builtin_amdgcn_mfma_f32_16x16x32_bf16(af, bfv, acc[nf], 0, 0, 0);
            }
        }
    }
#undef K1_LOAD

    // scatter Q, K, V^T (C-layout: row = w*16 + l4*4 + j, col = nf*16 + l15)
#pragma unroll
    for (int nf = 0; nf < 6; ++nf) {
        int c = nf * 16 + l15;
#pragma unroll
        for (int j = 0; j < 4; ++j) {
            int row = w * 16 + l4 * 4 + j;
            short v = f2bf(acc[nf][j]);
            if (c < 32)       Qs[row][c] = v;
            else if (c < 64)  Ks[row][c - 32] = v;
            else              Vt[c - 64][row] = v;
        }
    }
    __syncthreads();

    // S^T = K @ Q^T : wave w holds j-rows [w*16,+16), i-cols 0..63.
    // Column softmax (over i) fully in-wave: i spans {nf, l15}.
    const float scale = 0.17677669529663687f;  // 1/sqrt(32)
    f32x4 sacc[4] = {};
    {
        bf16x8 ak = *(const bf16x8*)&Ks[w * 16 + l15][l4 * 8];
#pragma unroll
        for (int nf = 0; nf < 4; ++nf) {
            bf16x8 bq = *(const bf16x8*)&Qs[nf * 16 + l15][l4 * 8];
            sacc[nf] = __builtin_amdgcn_mfma_f32_16x16x32_bf16(ak, bq, sacc[nf], 0, 0, 0);
        }
    }
#pragma unroll
    for (int nf = 0; nf < 4; ++nf) sacc[nf] *= scale;
#pragma unroll
    for (int jj = 0; jj < 4; ++jj) {
        float mx = fmaxf(fmaxf(sacc[0][jj], sacc[1][jj]),
                         fmaxf(sacc[2][jj], sacc[3][jj]));
        mx = fmaxf(mx, __shfl_xor(mx, 1, 64));
        mx = fmaxf(mx, __shfl_xor(mx, 2, 64));
        mx = fmaxf(mx, __shfl_xor(mx, 4, 64));
        mx = fmaxf(mx, __shfl_xor(mx, 8, 64));
        float e0 = __expf(sacc[0][jj] - mx);
        float e1 = __expf(sacc[1][jj] - mx);
        float e2 = __expf(sacc[2][jj] - mx);
        float e3 = __expf(sacc[3][jj] - mx);
        float ss = e0 + e1 + e2 + e3;
        ss += __shfl_xor(ss, 1, 64);
        ss += __shfl_xor(ss, 2, 64);
        ss += __shfl_xor(ss, 4, 64);
        ss += __shfl_xor(ss, 8, 64);
        float inv = 1.0f / ss;
        sacc[0][jj] = e0 * inv; sacc[1][jj] = e1 * inv;
        sacc[2][jj] = e2 * inv; sacc[3][jj] = e3 * inv;
    }
    // write P[i][j]: lane -> i = nf*16+l15, j-quad = w*16 + l4*4 (b64 stores)
#pragma unroll
    for (int nf = 0; nf < 4; ++nf) {
        short4v pq;
        pq[0] = f2bf(sacc[nf][0]); pq[1] = f2bf(sacc[nf][1]);
        pq[2] = f2bf(sacc[nf][2]); pq[3] = f2bf(sacc[nf][3]);
        *(short4v*)&Pm[nf * 16 + l15][w * 16 + l4 * 4] = pq;
    }
    __syncthreads();

    // attn = P @ V : wave w rows [w*16,+16), cols d 0..31
    f32x4 pv[2] = {};
#pragma unroll
    for (int ki = 0; ki < 2; ++ki) {
        bf16x8 ap = *(const bf16x8*)&Pm[w * 16 + l15][ki * 32 + l4 * 8];
#pragma unroll
        for (int nf = 0; nf < 2; ++nf) {
            bf16x8 bv = *(const bf16x8*)&Vt[nf * 16 + l15][ki * 32 + l4 * 8];
            pv[nf] = __builtin_amdgcn_mfma_f32_16x16x32_bf16(ap, bv, pv[nf], 0, 0, 0);
        }
    }
#pragma unroll
    for (int nf = 0; nf < 2; ++nf)
#pragma unroll
        for (int j = 0; j < 4; ++j)
            attn[(size_t)(s * 64 + w * 16 + l4 * 4 + j) * 256 + h * 32 + nf * 16 + l15]
                = f2bf(pv[nf][j]);
}

// ---------------------------------------------------------------------------
// K2: fused tail for 16 rows: out-proj+residual, LN1, MLP(silu)+residual, LN2.
// Grid 256 blocks x 512 threads (8 waves). Weight fragments prefetched one
// K-step ahead from global (L2-resident).
// ---------------------------------------------------------------------------
__global__ __launch_bounds__(512) void k2_tail(
    const short* __restrict__ attnbf, const short* __restrict__ WoutT,
    const short* __restrict__ WmlpT, const float* __restrict__ h_one,
    const float* __restrict__ b_mlp,
    const float* __restrict__ ln1_s, const float* __restrict__ ln1_b,
    const float* __restrict__ ln2_s, const float* __restrict__ ln2_b,
    float* __restrict__ out)
{
    const int r0 = blockIdx.x * 16;

    __shared__ short Abf[16][264];
    __shared__ float H1[16][260];
    __shared__ short L1[16][264];

    const int tid = threadIdx.x;
    const int lane = tid & 63;
    const int w = tid >> 6;           // 0..7
    const int l15 = lane & 15;
    const int l4 = lane >> 4;

    const size_t wrow0 = (size_t)(w * 32 + l15) * 256;       // nf=0 weight row
    const size_t wrow1 = (size_t)(w * 32 + 16 + l15) * 256;  // nf=1 weight row

    {
        int r = tid >> 5, c8 = (tid & 31) * 8;
        *(bf16x8*)&Abf[r][c8] = *(const bf16x8*)&attnbf[(size_t)(r0 + r) * 256 + c8];
    }
    __syncthreads();

    // GEMM1: wave w covers cols [w*32, +32), M=16, K=256 (B prefetched)
    f32x4 acc[2] = {};
    {
        bf16x8 bcur0 = *(const bf16x8*)&WoutT[wrow0 + l4 * 8];
        bf16x8 bcur1 = *(const bf16x8*)&WoutT[wrow1 + l4 * 8];
#pragma unroll
        for (int k0 = 0; k0 < 256; k0 += 32) {
            bf16x8 bnxt0, bnxt1;
            if (k0 < 224) {
                bnxt0 = *(const bf16x8*)&WoutT[wrow0 + k0 + 32 + l4 * 8];
                bnxt1 = *(const bf16x8*)&WoutT[wrow1 + k0 + 32 + l4 * 8];
            }
            bf16x8 af = *(const bf16x8*)&Abf[l15][k0 + l4 * 8];
            acc[0] = __builtin_amdgcn_mfma_f32_16x16x32_bf16(af, bcur0, acc[0], 0, 0, 0);
            acc[1] = __builtin_amdgcn_mfma_f32_16x16x32_bf16(af, bcur1, acc[1], 0, 0, 0);
            bcur0 = bnxt0; bcur1 = bnxt1;
        }
    }
#pragma unroll
    for (int nf = 0; nf < 2; ++nf) {
        int col = w * 32 + nf * 16 + l15;
#pragma unroll
        for (int j = 0; j < 4; ++j) {
            int row = l4 * 4 + j;
            H1[row][col] = acc[nf][j] + h_one[(size_t)(r0 + row) * 256 + col];
        }
    }
    __syncthreads();

    // LN1
    {
        float4 sc = *(const float4*)&ln1_s[lane * 4];
        float4 bi = *(const float4*)&ln1_b[lane * 4];
#pragma unroll
        for (int rr = 0; rr < 2; ++rr) {
            int row = w * 2 + rr;
            float4 v = *(const float4*)&H1[row][lane * 4];
            float su = v.x + v.y + v.z + v.w;
#pragma unroll
            for (int off = 32; off > 0; off >>= 1) su += __shfl_xor(su, off, 64);
            float mu = su * (1.0f / 256.0f);
            float dx = v.x - mu, dy = v.y - mu, dz = v.z - mu, dw = v.w - mu;
            float s2 = dx * dx + dy * dy + dz * dz + dw * dw;
#pragma unroll
            for (int off = 32; off > 0; off >>= 1) s2 += __shfl_xor(s2, off, 64);
            float inv = rsqrtf(s2 * (1.0f / 256.0f) + LN_EPS);
            float4 o;
            o.x = dx * inv * sc.x + bi.x;
            o.y = dy * inv * sc.y + bi.y;
            o.z = dz * inv * sc.z + bi.z;
            o.w = dw * inv * sc.w + bi.w;
            *(float4*)&H1[row][lane * 4] = o;
            short4v ob;
            ob[0] = f2bf(o.x); ob[1] = f2bf(o.y); ob[2] = f2bf(o.z); ob[3] = f2bf(o.w);
            *(short4v*)&L1[row][lane * 4] = ob;
        }
    }
    __syncthreads();

    // GEMM2: h2 = H1 + silu(L1 @ WmlpT + b_mlp) (B prefetched)
    f32x4 acc2[2] = {};
    {
        bf16x8 bcur0 = *(const bf16x8*)&WmlpT[wrow0 + l4 * 8];
        bf16x8 bcur1 = *(const bf16x8*)&WmlpT[wrow1 + l4 * 8];
#pragma unroll
        for (int k0 = 0; k0 < 256; k0 += 32) {
            bf16x8 bnxt0, bnxt1;
            if (k0 < 224) {
                bnxt0 = *(const bf16x8*)&WmlpT[wrow0 + k0 + 32 + l4 * 8];
                bnxt1 = *(const bf16x8*)&WmlpT[wrow1 + k0 + 32 + l4 * 8];
            }
            bf16x8 af = *(const bf16x8*)&L1[l15][k0 + l4 * 8];
            acc2[0] = __builtin_amdgcn_mfma_f32_16x16x32_bf16(af, bcur0, acc2[0], 0, 0, 0);
            acc2[1] = __builtin_amdgcn_mfma_f32_16x16x32_bf16(af, bcur1, acc2[1], 0, 0, 0);
            bcur0 = bnxt0; bcur1 = bnxt1;
        }
    }
#pragma unroll
    for (int nf = 0; nf < 2; ++nf) {
        int col = w * 32 + nf * 16 + l15;
        float bm = b_mlp[col];
#pragma unroll
        for (int j = 0; j < 4; ++j) {
            int row = l4 * 4 + j;
            float v = acc2[nf][j] + bm;
            float sg = 1.0f / (1.0f + __expf(-v));
            H1[row][col] = H1[row][col] + v * sg;   // same-lane RMW
        }
    }
    __syncthreads();

    // LN2 -> out
    {
        float4 sc = *(const float4*)&ln2_s[lane * 4];
        float4 bi = *(const float4*)&ln2_b[lane * 4];
#pragma unroll
        for (int rr = 0; rr < 2; ++rr) {
            int row = w * 2 + rr;
            float4 v = *(const float4*)&H1[row][lane * 4];
            float su = v.x + v.y + v.z + v.w;
#pragma unroll
            for (int off = 32; off > 0; off >>= 1) su += __shfl_xor(su, off, 64);
            float mu = su * (1.0f / 256.0f);
            float dx = v.x - mu, dy = v.y - mu, dz = v.z - mu, dw = v.w - mu;
            float s2 = dx * dx + dy * dy + dz * dz + dw * dw;
#pragma unroll
            for (int off = 32; off > 0; off >>= 1) s2 += __shfl_xor(s2, off, 64);
            float inv = rsqrtf(s2 * (1.0f / 256.0f) + LN_EPS);
            float4 o;
            o.x = dx * inv * sc.x + bi.x;
            o.y = dy * inv * sc.y + bi.y;
            o.z = dz * inv * sc.z + bi.z;
            o.w = dw * inv * sc.w + bi.w;
            *(float4*)&out[(size_t)(r0 + row) * 256 + lane * 4] = o;
        }
    }
}

// ---------------------------------------------------------------------------
extern "C" void kernel_launch(void* const* d_in, const int* in_sizes, int n_in,
                              void* d_out, int out_size, void* d_ws, size_t ws_size,
                              hipStream_t stream)
{
    const float* h_one = (const float*)d_in[0];
    const float* W_qkv = (const float*)d_in[1];
    const float* W_out = (const float*)d_in[2];
    const float* ln1_s = (const float*)d_in[3];
    const float* ln1_b = (const float*)d_in[4];
    const float* W_mlp = (const float*)d_in[5];
    const float* b_mlp = (const float*)d_in[6];
    const float* ln2_s = (const float*)d_in[7];
    const float* ln2_b = (const float*)d_in[8];
    float* out = (float*)d_out;

    char* ws = (char*)d_ws;
    short* attn_bf = (short*)ws;                 // 4096*256 bf16 = 2MB
    short* WoutT   = (short*)(ws + 2097152);     // 256*256 bf16 = 128KB
    short* WmlpT   = WoutT + 256 * 256;

    k1_qkv_attn<<<544, 256, 0, stream>>>(h_one, W_qkv, W_out, W_mlp,
                                         attn_bf, WoutT, WmlpT);
    k2_tail<<<256, 512, 0, stream>>>(attn_bf, WoutT, WmlpT, h_one, b_mlp,
                                     ln1_s, ln1_b, ln2_s, ln2_b, out);
}